// Round 5
// baseline (184.122 us; speedup 1.0000x reference)
//
#include <hip/hip_runtime.h>

typedef __attribute__((ext_vector_type(8))) short short8_t;
typedef __attribute__((ext_vector_type(4))) float f32x4;

namespace {
constexpr int T_CTX  = 4096;
constexpr int E_DIM  = 1024;
constexpr int H_DIM  = 64;
constexpr int B_SZ   = 4;
constexpr int M_ROWS = B_SZ * T_CTX; // 16384
}

__device__ __forceinline__ unsigned short f2bf(float f) {
    unsigned u = __builtin_bit_cast(unsigned, f);
    u += 0x7fffu + ((u >> 16) & 1u);          // RNE
    return (unsigned short)(u >> 16);
}
__device__ __forceinline__ unsigned pack2(unsigned short lo, unsigned short hi) {
    return (unsigned)lo | ((unsigned)hi << 16);
}
// swizzled ushort index into a row-major [rows][64] bf16 LDS tile
__device__ __forceinline__ int swz(int row, int col) {
    return row * 64 + (col ^ ((row & 7) << 3));
}

// ---------------------------------------------------------------------------
// Weight prep: W[1024][64] fp32 -> Wt[64][1024] bf16 (per matrix), via LDS.
// ---------------------------------------------------------------------------
__global__ __launch_bounds__(256)
void prep_weights(const float* __restrict__ Wq, const float* __restrict__ Wk,
                  const float* __restrict__ Wv, unsigned short* __restrict__ wt)
{
    const int mat = blockIdx.y;
    const float* W = (mat == 0) ? Wq : (mat == 1) ? Wk : Wv;
    unsigned short* out = wt + (size_t)mat * H_DIM * E_DIM;
    __shared__ float Ls[64][65];
    const int tid = threadIdx.x;
    const int kb = blockIdx.x * 64;
    #pragma unroll
    for (int j = 0; j < 4; ++j) {
        int p = j * 256 + tid;
        int kr = p >> 4, c4 = (p & 15) * 4;
        float4 w4 = *reinterpret_cast<const float4*>(&W[(size_t)(kb + kr) * H_DIM + c4]);
        Ls[c4 + 0][kr] = w4.x; Ls[c4 + 1][kr] = w4.y;
        Ls[c4 + 2][kr] = w4.z; Ls[c4 + 3][kr] = w4.w;
    }
    __syncthreads();
    #pragma unroll
    for (int j = 0; j < 2; ++j) {
        int p = j * 256 + tid;
        int n = p >> 3, c8 = (p & 7) * 8;
        uint4 w;
        w.x = pack2(f2bf(Ls[n][c8 + 0]), f2bf(Ls[n][c8 + 1]));
        w.y = pack2(f2bf(Ls[n][c8 + 2]), f2bf(Ls[n][c8 + 3]));
        w.z = pack2(f2bf(Ls[n][c8 + 4]), f2bf(Ls[n][c8 + 5]));
        w.w = pack2(f2bf(Ls[n][c8 + 6]), f2bf(Ls[n][c8 + 7]));
        *reinterpret_cast<uint4*>(&out[(size_t)n * E_DIM + kb + c8]) = w;
    }
}

// ---------------------------------------------------------------------------
// Fused QKV projection, 2-way K-split. Block = 32 rows x 4 waves:
// wave = (rpair, khalf); each wave streams its 512-k half barrier-free,
// then LDS partial-sum merge. q pre-scaled 0.125; v transposed vt[b][h][t].
// ---------------------------------------------------------------------------
__global__ __launch_bounds__(256)
void proj_kernel(const float* __restrict__ x, const unsigned short* __restrict__ wt,
                 const float* __restrict__ bq, const float* __restrict__ bk,
                 const float* __restrict__ bv,
                 unsigned short* __restrict__ qb, unsigned short* __restrict__ kb,
                 unsigned short* __restrict__ vtb)
{
    const int tid = threadIdx.x;
    const int lane = tid & 63, wv = tid >> 6;
    const int l15 = lane & 15, lg = lane >> 4;
    const int kof = lg * 8;

    const int rpair = wv >> 1;                // which 16-row group
    const int kh    = wv & 1;                 // which k half
    const int m0    = blockIdx.x * 32 + rpair * 16;
    const int batch = m0 >> 12;
    const int t0    = m0 & (T_CTX - 1);

    f32x4 acc[3][4] = {};
    const float* xrow = &x[(size_t)(m0 + l15) * E_DIM + kof];
    const int kbeg = kh * 512;

    #pragma unroll 2
    for (int k0 = kbeg; k0 < kbeg + 512; k0 += 32) {
        const float4 xa = *reinterpret_cast<const float4*>(xrow + k0);
        const float4 xb = *reinterpret_cast<const float4*>(xrow + k0 + 4);
        short8_t a;
        a[0] = (short)f2bf(xa.x); a[1] = (short)f2bf(xa.y);
        a[2] = (short)f2bf(xa.z); a[3] = (short)f2bf(xa.w);
        a[4] = (short)f2bf(xb.x); a[5] = (short)f2bf(xb.y);
        a[6] = (short)f2bf(xb.z); a[7] = (short)f2bf(xb.w);
        #pragma unroll
        for (int mat = 0; mat < 3; ++mat)
            #pragma unroll
            for (int oc = 0; oc < 4; ++oc) {
                short8_t b = *reinterpret_cast<const short8_t*>(
                    &wt[((size_t)mat * H_DIM + oc * 16 + l15) * E_DIM + k0 + kof]);
                acc[mat][oc] = __builtin_amdgcn_mfma_f32_16x16x32_bf16(
                    a, b, acc[mat][oc], 0, 0, 0);
            }
    }

    __shared__ float Ms[2][64][48];
    if (kh == 1) {
        #pragma unroll
        for (int mat = 0; mat < 3; ++mat)
            #pragma unroll
            for (int oc = 0; oc < 4; ++oc)
                #pragma unroll
                for (int r = 0; r < 4; ++r)
                    Ms[rpair][lane][(mat * 4 + oc) * 4 + r] = acc[mat][oc][r];
    }
    __syncthreads();
    if (kh == 0) {
        #pragma unroll
        for (int mat = 0; mat < 3; ++mat)
            #pragma unroll
            for (int oc = 0; oc < 4; ++oc)
                #pragma unroll
                for (int r = 0; r < 4; ++r)
                    acc[mat][oc][r] += Ms[rpair][lane][(mat * 4 + oc) * 4 + r];
        #pragma unroll
        for (int oc = 0; oc < 4; ++oc) {
            const int col = oc * 16 + l15;
            const float bqv = bq[col], bkv = bk[col], bvv = bv[col];
            #pragma unroll
            for (int r = 0; r < 4; ++r) {
                const int row = lg * 4 + r;
                qb[(size_t)(m0 + row) * H_DIM + col] = f2bf((acc[0][oc][r] + bqv) * 0.125f);
                kb[(size_t)(m0 + row) * H_DIM + col] = f2bf(acc[1][oc][r] + bkv);
                vtb[((size_t)batch * H_DIM + col) * T_CTX + t0 + row] =
                    f2bf(acc[2][oc][r] + bvv);
            }
        }
    }
}

// ---------------------------------------------------------------------------
// Causal flash attention, 8-way split-KV. Block = (strip, batch), 512 thr;
// 8 waves take kv tiles stride-8 with private (m,l,o); loop is barrier-free;
// end: barrier + publish partials into an ALIASED 33KB LDS buffer (reuses
// the per-wave P region) + log-sum-exp merge.
// ---------------------------------------------------------------------------
__global__ __launch_bounds__(512, 8)
void attn_kernel(const unsigned short* __restrict__ qg,
                 const unsigned short* __restrict__ kg,
                 const unsigned short* __restrict__ vt,
                 float* __restrict__ outp)
{
    const int tid  = threadIdx.x;
    const int lane = tid & 63, wv = tid >> 6;   // wv 0..7
    const int l15 = lane & 15, lg = lane >> 4;
    const int kof = lg * 8;

    const int idx   = 1023 - blockIdx.x;        // heavy strips first
    const int st    = idx >> 2;                 // 0..255
    const int batch = idx & 3;
    const int q0    = st * 16;
    const int nkv   = st / 4 + 1;               // 64-wide kv tiles
    const size_t rbase = (size_t)batch * T_CTX;
    const size_t vbase = (size_t)batch * H_DIM * T_CTX;

    __shared__ float smem[8448];                // 33 KB: Pt (16KB) ∪ merge (33KB)
    unsigned short* Pt = (unsigned short*)smem;
    const int pbase = wv * 1024;                // per-wave 2KB P region

    // Q fragments (pre-scaled by 0.125 in proj)
    short8_t qa[2];
    #pragma unroll
    for (int hs = 0; hs < 2; ++hs)
        qa[hs] = *reinterpret_cast<const short8_t*>(
            &qg[(rbase + q0 + l15) * H_DIM + hs * 32 + kof]);

    f32x4 o[4] = {};
    float mrow[4] = {-1e30f, -1e30f, -1e30f, -1e30f};
    float lrow[4] = {};

    for (int kt = wv; kt < nkv; kt += 8) {
        const int k0 = kt * 64;

        // S = Q K^T  (K fragments short-lived, per-hs)
        f32x4 s[4] = {};
        #pragma unroll
        for (int hs = 0; hs < 2; ++hs) {
            short8_t kf[4];
            #pragma unroll
            for (int ct = 0; ct < 4; ++ct)
                kf[ct] = *reinterpret_cast<const short8_t*>(
                    &kg[(rbase + k0 + ct * 16 + l15) * H_DIM + hs * 32 + kof]);
            #pragma unroll
            for (int ct = 0; ct < 4; ++ct)
                s[ct] = __builtin_amdgcn_mfma_f32_16x16x32_bf16(
                    qa[hs], kf[ct], s[ct], 0, 0, 0);
        }

        if (kt == nkv - 1) {    // only the last strip tile crosses the diagonal
            #pragma unroll
            for (int ct = 0; ct < 4; ++ct)
                #pragma unroll
                for (int r = 0; r < 4; ++r)
                    if (k0 + ct * 16 + l15 > q0 + lg * 4 + r) s[ct][r] = -1e30f;
        }

        // online softmax (wave-local)
        #pragma unroll
        for (int r = 0; r < 4; ++r) {
            float mx = fmaxf(fmaxf(s[0][r], s[1][r]), fmaxf(s[2][r], s[3][r]));
            mx = fmaxf(mx, __shfl_xor(mx, 1));
            mx = fmaxf(mx, __shfl_xor(mx, 2));
            mx = fmaxf(mx, __shfl_xor(mx, 4));
            mx = fmaxf(mx, __shfl_xor(mx, 8));
            const float newm = fmaxf(mrow[r], mx);
            const float cf = __expf(mrow[r] - newm);
            float rl = 0.f;
            #pragma unroll
            for (int ct = 0; ct < 4; ++ct) {
                float p = __expf(s[ct][r] - newm);
                rl += p;
                Pt[pbase + swz(lg * 4 + r, ct * 16 + l15)] = f2bf(p);
            }
            rl += __shfl_xor(rl, 1);
            rl += __shfl_xor(rl, 2);
            rl += __shfl_xor(rl, 4);
            rl += __shfl_xor(rl, 8);
            lrow[r] = lrow[r] * cf + rl;
            mrow[r] = newm;
            #pragma unroll
            for (int oc = 0; oc < 4; ++oc) o[oc][r] *= cf;
        }

        // V fragments (after softmax: TLP hides the latency, VGPR stays low)
        short8_t vf[8];
        #pragma unroll
        for (int oc = 0; oc < 4; ++oc)
            #pragma unroll
            for (int ks = 0; ks < 2; ++ks)
                vf[oc * 2 + ks] = *reinterpret_cast<const short8_t*>(
                    &vt[vbase + (size_t)(oc * 16 + l15) * T_CTX + k0 + ks * 32 + kof]);

        // O += P V
        #pragma unroll
        for (int ks = 0; ks < 2; ++ks) {
            short8_t pa = *reinterpret_cast<const short8_t*>(
                &Pt[pbase + swz(l15, ks * 32 + kof)]);
            #pragma unroll
            for (int oc = 0; oc < 4; ++oc)
                o[oc] = __builtin_amdgcn_mfma_f32_16x16x32_bf16(
                    pa, vf[oc * 2 + ks], o[oc], 0, 0, 0);
        }
    }

    __syncthreads();   // everyone done with P regions -> safe to alias

    // publish partials: Lo[w][row][col] at smem[w*1024 + row*64 + col],
    // Lm at smem[8192 + w*16 + row], Ll at smem[8320 + w*16 + row]
    #pragma unroll
    for (int oc = 0; oc < 4; ++oc)
        #pragma unroll
        for (int r = 0; r < 4; ++r)
            smem[wv * 1024 + (lg * 4 + r) * 64 + oc * 16 + l15] = o[oc][r];
    if (l15 == 0) {
        #pragma unroll
        for (int r = 0; r < 4; ++r) {
            smem[8192 + wv * 16 + lg * 4 + r] = mrow[r];
            smem[8320 + wv * 16 + lg * 4 + r] = lrow[r];
        }
    }
    __syncthreads();

    // merge: thread -> (row, 2 cols)
    {
        const int row = tid >> 5;
        const int c2  = (tid & 31) * 2;
        float M = -1e30f;
        #pragma unroll
        for (int w = 0; w < 8; ++w) M = fmaxf(M, smem[8192 + w * 16 + row]);
        float L = 0.f, a0 = 0.f, a1 = 0.f;
        #pragma unroll
        for (int w = 0; w < 8; ++w) {
            const float e = __expf(smem[8192 + w * 16 + row] - M);
            L += e * smem[8320 + w * 16 + row];
            a0 += e * smem[w * 1024 + row * 64 + c2];
            a1 += e * smem[w * 1024 + row * 64 + c2 + 1];
        }
        const float inv = 1.0f / L;
        float2 rr; rr.x = a0 * inv; rr.y = a1 * inv;
        *reinterpret_cast<float2*>(&outp[(rbase + q0 + row) * H_DIM + c2]) = rr;
    }
}

extern "C" void kernel_launch(void* const* d_in, const int* in_sizes, int n_in,
                              void* d_out, int out_size, void* d_ws, size_t ws_size,
                              hipStream_t stream) {
    const float* x  = (const float*)d_in[0];
    const float* Wq = (const float*)d_in[1];
    const float* bq = (const float*)d_in[2];
    const float* Wk = (const float*)d_in[3];
    const float* bk = (const float*)d_in[4];
    const float* Wv = (const float*)d_in[5];
    const float* bv = (const float*)d_in[6];
    float* out = (float*)d_out;

    // ws (ushort): Wt[3*64*1024] | q[16384*64] | k[16384*64] | vt[4*64*4096]
    unsigned short* wt  = (unsigned short*)d_ws;
    unsigned short* qb  = wt + 3 * H_DIM * E_DIM;
    unsigned short* kb  = qb + (size_t)M_ROWS * H_DIM;
    unsigned short* vtb = kb + (size_t)M_ROWS * H_DIM;

    prep_weights<<<dim3(E_DIM / 64, 3), 256, 0, stream>>>(Wq, Wk, Wv, wt);
    proj_kernel<<<dim3(M_ROWS / 32), 256, 0, stream>>>(x, wt, bq, bk, bv, qb, kb, vtb);
    attn_kernel<<<dim3((T_CTX / 16) * B_SZ), 512, 0, stream>>>(qb, kb, vtb, out);
}

// Round 6
// 127.668 us; speedup vs baseline: 1.4422x; 1.4422x over previous
//
#include <hip/hip_runtime.h>

typedef __attribute__((ext_vector_type(8))) short short8_t;
typedef __attribute__((ext_vector_type(4))) float f32x4;

namespace {
constexpr int T_CTX  = 4096;
constexpr int E_DIM  = 1024;
constexpr int H_DIM  = 64;
constexpr int B_SZ   = 4;
constexpr int M_ROWS = B_SZ * T_CTX; // 16384
// 1/sqrt(H) * log2(e): S lands in log2 domain -> softmax via exp2
constexpr float SCALE_Q = 0.125f * 1.4426950408889634f;
}

__device__ __forceinline__ unsigned short f2bf(float f) {
    unsigned u = __builtin_bit_cast(unsigned, f);
    u += 0x7fffu + ((u >> 16) & 1u);          // RNE
    return (unsigned short)(u >> 16);
}
__device__ __forceinline__ unsigned pack2(unsigned short lo, unsigned short hi) {
    return (unsigned)lo | ((unsigned)hi << 16);
}
// packed f32x2 -> bf16x2 (lo in low half)
__device__ __forceinline__ unsigned cvtpk(float lo, float hi) {
    unsigned r;
    asm("v_cvt_pk_bf16_f32 %0, %1, %2" : "=v"(r) : "v"(lo), "v"(hi));
    return r;
}
// swizzled ushort index into a row-major [rows][64] bf16 LDS tile
__device__ __forceinline__ int swz(int row, int col) {
    return row * 64 + (col ^ ((row & 7) << 3));
}

// ---------------------------------------------------------------------------
// Weight prep: W[1024][64] fp32 -> Wt[64][1024] bf16 (per matrix), via LDS.
// ---------------------------------------------------------------------------
__global__ __launch_bounds__(256)
void prep_weights(const float* __restrict__ Wq, const float* __restrict__ Wk,
                  const float* __restrict__ Wv, unsigned short* __restrict__ wt)
{
    const int mat = blockIdx.y;
    const float* W = (mat == 0) ? Wq : (mat == 1) ? Wk : Wv;
    unsigned short* out = wt + (size_t)mat * H_DIM * E_DIM;
    __shared__ float Ls[64][65];
    const int tid = threadIdx.x;
    const int kb = blockIdx.x * 64;
    #pragma unroll
    for (int j = 0; j < 4; ++j) {
        int p = j * 256 + tid;
        int kr = p >> 4, c4 = (p & 15) * 4;
        float4 w4 = *reinterpret_cast<const float4*>(&W[(size_t)(kb + kr) * H_DIM + c4]);
        Ls[c4 + 0][kr] = w4.x; Ls[c4 + 1][kr] = w4.y;
        Ls[c4 + 2][kr] = w4.z; Ls[c4 + 3][kr] = w4.w;
    }
    __syncthreads();
    #pragma unroll
    for (int j = 0; j < 2; ++j) {
        int p = j * 256 + tid;
        int n = p >> 3, c8 = (p & 7) * 8;
        uint4 w;
        w.x = pack2(f2bf(Ls[n][c8 + 0]), f2bf(Ls[n][c8 + 1]));
        w.y = pack2(f2bf(Ls[n][c8 + 2]), f2bf(Ls[n][c8 + 3]));
        w.z = pack2(f2bf(Ls[n][c8 + 4]), f2bf(Ls[n][c8 + 5]));
        w.w = pack2(f2bf(Ls[n][c8 + 6]), f2bf(Ls[n][c8 + 7]));
        *reinterpret_cast<uint4*>(&out[(size_t)n * E_DIM + kb + c8]) = w;
    }
}

// ---------------------------------------------------------------------------
// Fused QKV projection, 4-way K-split. Block = one 16-row group x 4 waves
// (k-quarters of 256). Barrier-free streaming per wave; LDS tree merge;
// wave-0 epilogue stages bf16 tiles in LDS and writes coalesced uint4.
// q pre-scaled by SCALE_Q; v written transposed vt[b][h][t].
// ---------------------------------------------------------------------------
__global__ __launch_bounds__(256)
void proj_kernel(const float* __restrict__ x, const unsigned short* __restrict__ wt,
                 const float* __restrict__ bq, const float* __restrict__ bk,
                 const float* __restrict__ bv,
                 unsigned short* __restrict__ qb, unsigned short* __restrict__ kb,
                 unsigned short* __restrict__ vtb)
{
    const int tid = threadIdx.x;
    const int lane = tid & 63, wv = tid >> 6;   // wv = k-quarter 0..3
    const int l15 = lane & 15, lg = lane >> 4;
    const int kof = lg * 8;

    const int m0    = blockIdx.x * 16;
    const int batch = m0 >> 12;
    const int t0    = m0 & (T_CTX - 1);

    f32x4 acc[3][4] = {};
    const float* xrow = &x[(size_t)(m0 + l15) * E_DIM + kof];
    const int kbeg = wv * 256;

    #pragma unroll 2
    for (int k0 = kbeg; k0 < kbeg + 256; k0 += 32) {
        const float4 xa = *reinterpret_cast<const float4*>(xrow + k0);
        const float4 xb = *reinterpret_cast<const float4*>(xrow + k0 + 4);
        uint4 au;
        au.x = cvtpk(xa.x, xa.y); au.y = cvtpk(xa.z, xa.w);
        au.z = cvtpk(xb.x, xb.y); au.w = cvtpk(xb.z, xb.w);
        const short8_t a = __builtin_bit_cast(short8_t, au);
        #pragma unroll
        for (int mat = 0; mat < 3; ++mat)
            #pragma unroll
            for (int oc = 0; oc < 4; ++oc) {
                short8_t b = *reinterpret_cast<const short8_t*>(
                    &wt[((size_t)mat * H_DIM + oc * 16 + l15) * E_DIM + k0 + kof]);
                acc[mat][oc] = __builtin_amdgcn_mfma_f32_16x16x32_bf16(
                    a, b, acc[mat][oc], 0, 0, 0);
            }
    }

    // ---- tree merge: (1,3) dump; (0,2) add; 2 dumps; 0 adds ----
    __shared__ float Ms[2][64][49];   // 25 KB, padded stride vs conflicts
    if (wv & 1) {
        #pragma unroll
        for (int mat = 0; mat < 3; ++mat)
            #pragma unroll
            for (int oc = 0; oc < 4; ++oc)
                #pragma unroll
                for (int r = 0; r < 4; ++r)
                    Ms[wv >> 1][lane][(mat * 4 + oc) * 4 + r] = acc[mat][oc][r];
    }
    __syncthreads();
    if ((wv & 1) == 0) {
        #pragma unroll
        for (int mat = 0; mat < 3; ++mat)
            #pragma unroll
            for (int oc = 0; oc < 4; ++oc)
                #pragma unroll
                for (int r = 0; r < 4; ++r)
                    acc[mat][oc][r] += Ms[wv >> 1][lane][(mat * 4 + oc) * 4 + r];
    }
    __syncthreads();
    if (wv == 2) {
        #pragma unroll
        for (int mat = 0; mat < 3; ++mat)
            #pragma unroll
            for (int oc = 0; oc < 4; ++oc)
                #pragma unroll
                for (int r = 0; r < 4; ++r)
                    Ms[0][lane][(mat * 4 + oc) * 4 + r] = acc[mat][oc][r];
    }
    __syncthreads();
    if (wv == 0) {
        #pragma unroll
        for (int mat = 0; mat < 3; ++mat)
            #pragma unroll
            for (int oc = 0; oc < 4; ++oc)
                #pragma unroll
                for (int r = 0; r < 4; ++r)
                    acc[mat][oc][r] += Ms[0][lane][(mat * 4 + oc) * 4 + r];

        unsigned short* stage = (unsigned short*)&Ms[1][0][0];  // 2KB reuse

        // q then k: stage swizzled [16][64] tile, read back coalesced
        #pragma unroll
        for (int mat = 0; mat < 2; ++mat) {
            const float* bias = mat ? bk : bq;
            const float sc = mat ? 1.0f : SCALE_Q;
            #pragma unroll
            for (int oc = 0; oc < 4; ++oc) {
                const float bb = bias[oc * 16 + l15];
                #pragma unroll
                for (int r = 0; r < 4; ++r)
                    stage[swz(lg * 4 + r, oc * 16 + l15)] =
                        f2bf((acc[mat][oc][r] + bb) * sc);
            }
            unsigned short* outg = mat ? kb : qb;
            const int row = lane >> 2, c = (lane & 3) * 16;
            uint4 w0 = *reinterpret_cast<const uint4*>(&stage[swz(row, c)]);
            uint4 w1 = *reinterpret_cast<const uint4*>(&stage[swz(row, c + 8)]);
            *reinterpret_cast<uint4*>(&outg[(size_t)(m0 + row) * H_DIM + c]) = w0;
            *reinterpret_cast<uint4*>(&outg[(size_t)(m0 + row) * H_DIM + c + 8]) = w1;
        }

        // v: stage transposed [h=64][t=16], write 32B-contiguous per h row
        #pragma unroll
        for (int oc = 0; oc < 4; ++oc) {
            const float bb = bv[oc * 16 + l15];
            const int h = oc * 16 + l15;
            uint2 pw;
            pw.x = cvtpk(acc[2][oc][0] + bb, acc[2][oc][1] + bb);
            pw.y = cvtpk(acc[2][oc][2] + bb, acc[2][oc][3] + bb);
            *reinterpret_cast<uint2*>(&stage[h * 16 + lg * 4]) = pw;
        }
        const int h = lane;
        uint4 v0 = *reinterpret_cast<const uint4*>(&stage[h * 16]);
        uint4 v1 = *reinterpret_cast<const uint4*>(&stage[h * 16 + 8]);
        unsigned short* vrow = &vtb[((size_t)batch * H_DIM + h) * T_CTX + t0];
        *reinterpret_cast<uint4*>(&vrow[0]) = v0;
        *reinterpret_cast<uint4*>(&vrow[8]) = v1;
    }
}

// ---------------------------------------------------------------------------
// Causal flash attention, 8-way split-KV, swapped-QK^T softmax.
// s = mfma(K, Q) -> S^T: each lane owns ONE q-row (l15) x 16 k-cols ->
// row-reduce = in-lane tree + 2 shfl; m,l are scalars; P^T written as
// 4x ds_write_b64 via v_cvt_pk_bf16_f32; exp2 domain (log2e folded into q).
// End: barrier + aliased-LDS log-sum-exp merge over the 8 partials.
// ---------------------------------------------------------------------------
__global__ __launch_bounds__(512)
void attn_kernel(const unsigned short* __restrict__ qg,
                 const unsigned short* __restrict__ kg,
                 const unsigned short* __restrict__ vt,
                 float* __restrict__ outp)
{
    const int tid  = threadIdx.x;
    const int lane = tid & 63, wv = tid >> 6;   // wv 0..7
    const int l15 = lane & 15, lg = lane >> 4;
    const int kof = lg * 8;

    const int idx   = 1023 - blockIdx.x;        // heavy strips first
    const int st    = idx >> 2;                 // 0..255
    const int batch = idx & 3;
    const int q0    = st * 16;
    const int nkv   = st / 4 + 1;               // 64-wide kv tiles
    const size_t rbase = (size_t)batch * T_CTX;
    const size_t vbase = (size_t)batch * H_DIM * T_CTX;

    __shared__ float smem[8448];                // 33 KB: Pt (16KB) ∪ merge (33KB)
    unsigned short* Pt = (unsigned short*)smem;
    const int pbase = wv * 1024;                // per-wave 2KB P region

    short8_t qa[2];
    #pragma unroll
    for (int hs = 0; hs < 2; ++hs)
        qa[hs] = *reinterpret_cast<const short8_t*>(
            &qg[(rbase + q0 + l15) * H_DIM + hs * 32 + kof]);

    f32x4 o[4] = {};
    float m = -1e30f, l = 0.f;

    for (int kt = wv; kt < nkv; kt += 8) {
        const int k0 = kt * 64;

        // S^T = K Q^T  (swapped operands)
        f32x4 s[4] = {};
        #pragma unroll
        for (int hs = 0; hs < 2; ++hs) {
            short8_t kf[4];
            #pragma unroll
            for (int ct = 0; ct < 4; ++ct)
                kf[ct] = *reinterpret_cast<const short8_t*>(
                    &kg[(rbase + k0 + ct * 16 + l15) * H_DIM + hs * 32 + kof]);
            #pragma unroll
            for (int ct = 0; ct < 4; ++ct)
                s[ct] = __builtin_amdgcn_mfma_f32_16x16x32_bf16(
                    kf[ct], qa[hs], s[ct], 0, 0, 0);
        }

        // causal mask: kcol = k0+ct*16+lg*4+r, qrow = q0+l15
        if (kt == nkv - 1) {
            #pragma unroll
            for (int ct = 0; ct < 4; ++ct)
                #pragma unroll
                for (int r = 0; r < 4; ++r)
                    if (k0 + ct * 16 + lg * 4 + r > q0 + l15) s[ct][r] = -1e30f;
        }

        // per-lane row softmax (q-row = l15)
        float cm[4];
        #pragma unroll
        for (int ct = 0; ct < 4; ++ct)
            cm[ct] = fmaxf(fmaxf(s[ct][0], s[ct][1]), fmaxf(s[ct][2], s[ct][3]));
        float mx = fmaxf(fmaxf(cm[0], cm[1]), fmaxf(cm[2], cm[3]));
        mx = fmaxf(mx, __shfl_xor(mx, 16));
        mx = fmaxf(mx, __shfl_xor(mx, 32));
        const float newm = fmaxf(m, mx);
        const float cf = exp2f(m - newm);
        m = newm;

        float rl = 0.f;
        #pragma unroll
        for (int ct = 0; ct < 4; ++ct) {
            const float p0 = exp2f(s[ct][0] - newm);
            const float p1 = exp2f(s[ct][1] - newm);
            const float p2 = exp2f(s[ct][2] - newm);
            const float p3 = exp2f(s[ct][3] - newm);
            rl += (p0 + p1) + (p2 + p3);
            uint2 pw;
            pw.x = cvtpk(p0, p1);
            pw.y = cvtpk(p2, p3);
            *reinterpret_cast<uint2*>(&Pt[pbase + swz(l15, ct * 16 + lg * 4)]) = pw;
        }
        rl += __shfl_xor(rl, 16);
        rl += __shfl_xor(rl, 32);
        l = l * cf + rl;

        // rescale o: cf for q-row lg*4+r lives in lane lg*4+r
        #pragma unroll
        for (int r = 0; r < 4; ++r) {
            const float cfr = __shfl(cf, lg * 4 + r);
            #pragma unroll
            for (int oc = 0; oc < 4; ++oc) o[oc][r] *= cfr;
        }

        // V fragments + O += P V  (P read back in A-operand layout)
        short8_t vf[8];
        #pragma unroll
        for (int oc = 0; oc < 4; ++oc)
            #pragma unroll
            for (int ks = 0; ks < 2; ++ks)
                vf[oc * 2 + ks] = *reinterpret_cast<const short8_t*>(
                    &vt[vbase + (size_t)(oc * 16 + l15) * T_CTX + k0 + ks * 32 + kof]);
        #pragma unroll
        for (int ks = 0; ks < 2; ++ks) {
            short8_t pa = *reinterpret_cast<const short8_t*>(
                &Pt[pbase + swz(l15, ks * 32 + kof)]);
            #pragma unroll
            for (int oc = 0; oc < 4; ++oc)
                o[oc] = __builtin_amdgcn_mfma_f32_16x16x32_bf16(
                    pa, vf[oc * 2 + ks], o[oc], 0, 0, 0);
        }
    }

    __syncthreads();   // all waves done with P regions -> safe to alias

    // publish partials: o at [wv*1024 + row*64 + col]; m at 8192+; l at 8320+
    #pragma unroll
    for (int oc = 0; oc < 4; ++oc)
        #pragma unroll
        for (int r = 0; r < 4; ++r)
            smem[wv * 1024 + (lg * 4 + r) * 64 + oc * 16 + l15] = o[oc][r];
    if (lg == 0) {
        smem[8192 + wv * 16 + l15] = m;
        smem[8320 + wv * 16 + l15] = l;
    }
    __syncthreads();

    // merge: thread -> (row, 2 cols); exp2 domain
    {
        const int row = tid >> 5;
        const int c2  = (tid & 31) * 2;
        float M = -1e30f;
        #pragma unroll
        for (int w = 0; w < 8; ++w) M = fmaxf(M, smem[8192 + w * 16 + row]);
        float L = 0.f, a0 = 0.f, a1 = 0.f;
        #pragma unroll
        for (int w = 0; w < 8; ++w) {
            const float e = exp2f(smem[8192 + w * 16 + row] - M);
            L += e * smem[8320 + w * 16 + row];
            a0 += e * smem[w * 1024 + row * 64 + c2];
            a1 += e * smem[w * 1024 + row * 64 + c2 + 1];
        }
        const float inv = 1.0f / L;
        float2 rr; rr.x = a0 * inv; rr.y = a1 * inv;
        *reinterpret_cast<float2*>(&outp[(rbase + q0 + row) * H_DIM + c2]) = rr;
    }
}

extern "C" void kernel_launch(void* const* d_in, const int* in_sizes, int n_in,
                              void* d_out, int out_size, void* d_ws, size_t ws_size,
                              hipStream_t stream) {
    const float* x  = (const float*)d_in[0];
    const float* Wq = (const float*)d_in[1];
    const float* bq = (const float*)d_in[2];
    const float* Wk = (const float*)d_in[3];
    const float* bk = (const float*)d_in[4];
    const float* Wv = (const float*)d_in[5];
    const float* bv = (const float*)d_in[6];
    float* out = (float*)d_out;

    // ws (ushort): Wt[3*64*1024] | q[16384*64] | k[16384*64] | vt[4*64*4096]
    unsigned short* wt  = (unsigned short*)d_ws;
    unsigned short* qb  = wt + 3 * H_DIM * E_DIM;
    unsigned short* kb  = qb + (size_t)M_ROWS * H_DIM;
    unsigned short* vtb = kb + (size_t)M_ROWS * H_DIM;

    prep_weights<<<dim3(E_DIM / 64, 3), 256, 0, stream>>>(Wq, Wk, Wv, wt);
    proj_kernel<<<dim3(M_ROWS / 16), 256, 0, stream>>>(x, wt, bq, bk, bv, qb, kb, vtb);
    attn_kernel<<<dim3((T_CTX / 16) * B_SZ), 512, 0, stream>>>(qb, kb, vtb, out);
}

// Round 7
// 100.548 us; speedup vs baseline: 1.8312x; 1.2697x over previous
//
#include <hip/hip_runtime.h>

typedef __attribute__((ext_vector_type(8))) short short8_t;
typedef __attribute__((ext_vector_type(4))) float f32x4;

namespace {
constexpr int T_CTX  = 4096;
constexpr int E_DIM  = 1024;
constexpr int H_DIM  = 64;
constexpr int B_SZ   = 4;
constexpr int M_ROWS = B_SZ * T_CTX; // 16384
// 1/sqrt(H) * log2(e): S lands in log2 domain -> softmax via exp2
constexpr float SCALE_Q = 0.125f * 1.4426950408889634f;
constexpr float DEFER_THR = 8.0f;    // log2 units; P bounded by 2^8
}

__device__ __forceinline__ unsigned short f2bf(float f) {
    unsigned u = __builtin_bit_cast(unsigned, f);
    u += 0x7fffu + ((u >> 16) & 1u);          // RNE
    return (unsigned short)(u >> 16);
}
__device__ __forceinline__ unsigned pack2(unsigned short lo, unsigned short hi) {
    return (unsigned)lo | ((unsigned)hi << 16);
}
__device__ __forceinline__ unsigned cvtpk(float lo, float hi) {
    unsigned r;
    asm("v_cvt_pk_bf16_f32 %0, %1, %2" : "=v"(r) : "v"(lo), "v"(hi));
    return r;
}
__device__ __forceinline__ float fexp2(float x) {   // guaranteed v_exp_f32
    float r;
    asm("v_exp_f32 %0, %1" : "=v"(r) : "v"(x));
    return r;
}
// swizzled ushort index into a row-major [rows][64] bf16 LDS tile
__device__ __forceinline__ int swz(int row, int col) {
    return row * 64 + (col ^ ((row & 7) << 3));
}

// ---------------------------------------------------------------------------
// Weight prep: W[1024][64] fp32 -> Wt[64][1024] bf16 (per matrix), via LDS.
// ---------------------------------------------------------------------------
__global__ __launch_bounds__(256)
void prep_weights(const float* __restrict__ Wq, const float* __restrict__ Wk,
                  const float* __restrict__ Wv, unsigned short* __restrict__ wt)
{
    const int mat = blockIdx.y;
    const float* W = (mat == 0) ? Wq : (mat == 1) ? Wk : Wv;
    unsigned short* out = wt + (size_t)mat * H_DIM * E_DIM;
    __shared__ float Ls[64][65];
    const int tid = threadIdx.x;
    const int kb = blockIdx.x * 64;
    #pragma unroll
    for (int j = 0; j < 4; ++j) {
        int p = j * 256 + tid;
        int kr = p >> 4, c4 = (p & 15) * 4;
        float4 w4 = *reinterpret_cast<const float4*>(&W[(size_t)(kb + kr) * H_DIM + c4]);
        Ls[c4 + 0][kr] = w4.x; Ls[c4 + 1][kr] = w4.y;
        Ls[c4 + 2][kr] = w4.z; Ls[c4 + 3][kr] = w4.w;
    }
    __syncthreads();
    #pragma unroll
    for (int j = 0; j < 2; ++j) {
        int p = j * 256 + tid;
        int n = p >> 3, c8 = (p & 7) * 8;
        uint4 w;
        w.x = pack2(f2bf(Ls[n][c8 + 0]), f2bf(Ls[n][c8 + 1]));
        w.y = pack2(f2bf(Ls[n][c8 + 2]), f2bf(Ls[n][c8 + 3]));
        w.z = pack2(f2bf(Ls[n][c8 + 4]), f2bf(Ls[n][c8 + 5]));
        w.w = pack2(f2bf(Ls[n][c8 + 6]), f2bf(Ls[n][c8 + 7]));
        *reinterpret_cast<uint4*>(&out[(size_t)n * E_DIM + kb + c8]) = w;
    }
}

// ---------------------------------------------------------------------------
// Fused QKV projection, 4-way K-split + 1-deep x prefetch. Block = one
// 16-row group x 4 waves (k-quarters of 256). LDS tree merge; wave-0
// epilogue stages bf16 tiles in LDS and writes coalesced.
// ---------------------------------------------------------------------------
__global__ __launch_bounds__(256)
void proj_kernel(const float* __restrict__ x, const unsigned short* __restrict__ wt,
                 const float* __restrict__ bq, const float* __restrict__ bk,
                 const float* __restrict__ bv,
                 unsigned short* __restrict__ qb, unsigned short* __restrict__ kb,
                 unsigned short* __restrict__ vtb)
{
    const int tid = threadIdx.x;
    const int lane = tid & 63, wv = tid >> 6;   // wv = k-quarter 0..3
    const int l15 = lane & 15, lg = lane >> 4;
    const int kof = lg * 8;

    const int m0    = blockIdx.x * 16;
    const int batch = m0 >> 12;
    const int t0    = m0 & (T_CTX - 1);

    f32x4 acc[3][4] = {};
    const float* xrow = &x[(size_t)(m0 + l15) * E_DIM + kof];
    const int kbeg = wv * 256;

    float4 xa = *reinterpret_cast<const float4*>(xrow + kbeg);
    float4 xb = *reinterpret_cast<const float4*>(xrow + kbeg + 4);

    for (int k0 = kbeg; k0 < kbeg + 256; k0 += 32) {
        const int kn = (k0 + 32 < kbeg + 256) ? k0 + 32 : kbeg;  // 1-deep prefetch
        float4 na = *reinterpret_cast<const float4*>(xrow + kn);
        float4 nb = *reinterpret_cast<const float4*>(xrow + kn + 4);
        uint4 au;
        au.x = cvtpk(xa.x, xa.y); au.y = cvtpk(xa.z, xa.w);
        au.z = cvtpk(xb.x, xb.y); au.w = cvtpk(xb.z, xb.w);
        const short8_t a = __builtin_bit_cast(short8_t, au);
        #pragma unroll
        for (int mat = 0; mat < 3; ++mat)
            #pragma unroll
            for (int oc = 0; oc < 4; ++oc) {
                short8_t b = *reinterpret_cast<const short8_t*>(
                    &wt[((size_t)mat * H_DIM + oc * 16 + l15) * E_DIM + k0 + kof]);
                acc[mat][oc] = __builtin_amdgcn_mfma_f32_16x16x32_bf16(
                    a, b, acc[mat][oc], 0, 0, 0);
            }
        xa = na; xb = nb;
    }

    // ---- tree merge: (1,3) dump; (0,2) add; 2 dumps; 0 adds ----
    __shared__ float Ms[2][64][49];
    if (wv & 1) {
        #pragma unroll
        for (int mat = 0; mat < 3; ++mat)
            #pragma unroll
            for (int oc = 0; oc < 4; ++oc)
                #pragma unroll
                for (int r = 0; r < 4; ++r)
                    Ms[wv >> 1][lane][(mat * 4 + oc) * 4 + r] = acc[mat][oc][r];
    }
    __syncthreads();
    if ((wv & 1) == 0) {
        #pragma unroll
        for (int mat = 0; mat < 3; ++mat)
            #pragma unroll
            for (int oc = 0; oc < 4; ++oc)
                #pragma unroll
                for (int r = 0; r < 4; ++r)
                    acc[mat][oc][r] += Ms[wv >> 1][lane][(mat * 4 + oc) * 4 + r];
    }
    __syncthreads();
    if (wv == 2) {
        #pragma unroll
        for (int mat = 0; mat < 3; ++mat)
            #pragma unroll
            for (int oc = 0; oc < 4; ++oc)
                #pragma unroll
                for (int r = 0; r < 4; ++r)
                    Ms[0][lane][(mat * 4 + oc) * 4 + r] = acc[mat][oc][r];
    }
    __syncthreads();
    if (wv == 0) {
        #pragma unroll
        for (int mat = 0; mat < 3; ++mat)
            #pragma unroll
            for (int oc = 0; oc < 4; ++oc)
                #pragma unroll
                for (int r = 0; r < 4; ++r)
                    acc[mat][oc][r] += Ms[0][lane][(mat * 4 + oc) * 4 + r];

        unsigned short* stage = (unsigned short*)&Ms[1][0][0];

        #pragma unroll
        for (int mat = 0; mat < 2; ++mat) {
            const float* bias = mat ? bk : bq;
            const float sc = mat ? 1.0f : SCALE_Q;
            #pragma unroll
            for (int oc = 0; oc < 4; ++oc) {
                const float bb = bias[oc * 16 + l15];
                #pragma unroll
                for (int r = 0; r < 4; ++r)
                    stage[swz(lg * 4 + r, oc * 16 + l15)] =
                        f2bf((acc[mat][oc][r] + bb) * sc);
            }
            unsigned short* outg = mat ? kb : qb;
            const int row = lane >> 2, c = (lane & 3) * 16;
            uint4 w0 = *reinterpret_cast<const uint4*>(&stage[swz(row, c)]);
            uint4 w1 = *reinterpret_cast<const uint4*>(&stage[swz(row, c + 8)]);
            *reinterpret_cast<uint4*>(&outg[(size_t)(m0 + row) * H_DIM + c]) = w0;
            *reinterpret_cast<uint4*>(&outg[(size_t)(m0 + row) * H_DIM + c + 8]) = w1;
        }

        #pragma unroll
        for (int oc = 0; oc < 4; ++oc) {
            const float bb = bv[oc * 16 + l15];
            const int h = oc * 16 + l15;
            uint2 pw;
            pw.x = cvtpk(acc[2][oc][0] + bb, acc[2][oc][1] + bb);
            pw.y = cvtpk(acc[2][oc][2] + bb, acc[2][oc][3] + bb);
            *reinterpret_cast<uint2*>(&stage[h * 16 + lg * 4]) = pw;
        }
        const int h = lane;
        uint4 v0 = *reinterpret_cast<const uint4*>(&stage[h * 16]);
        uint4 v1 = *reinterpret_cast<const uint4*>(&stage[h * 16 + 8]);
        unsigned short* vrow = &vtb[((size_t)batch * H_DIM + h) * T_CTX + t0];
        *reinterpret_cast<uint4*>(&vrow[0]) = v0;
        *reinterpret_cast<uint4*>(&vrow[8]) = v1;
    }
}

// ---------------------------------------------------------------------------
// Causal flash attention: 32 q-rows per wave, 8-way split-KV per block.
// Block = (32-row strip, batch), 512 thr. Swapped QK^T (lane owns q-rows
// l15 and 16+l15), defer-max, exp2 domain, v_exp asm. End: two-phase flat
// LSE merge (lo rows, hi rows) in aliased 33KB LDS.
// ---------------------------------------------------------------------------
__global__ __launch_bounds__(512)
void attn_kernel(const unsigned short* __restrict__ qg,
                 const unsigned short* __restrict__ kg,
                 const unsigned short* __restrict__ vt,
                 float* __restrict__ outp)
{
    const int tid  = threadIdx.x;
    const int lane = tid & 63, wv = tid >> 6;   // wv 0..7
    const int l15 = lane & 15, lg = lane >> 4;
    const int kof = lg * 8;

    const int idx   = 511 - blockIdx.x;         // heavy strips first
    const int st    = idx >> 2;                 // 0..127 (32-row strips)
    const int batch = idx & 3;
    const int q0    = st * 32;
    const int nkv   = st / 2 + 1;               // 64-wide kv tiles
    const size_t rbase = (size_t)batch * T_CTX;
    const size_t vbase = (size_t)batch * H_DIM * T_CTX;

    __shared__ float smem[8448];                // Pt (32KB) ∪ merge (33KB)
    unsigned short* Pt = (unsigned short*)smem;
    const int pbase = wv * 2048;                // per-wave [32][64] bf16

    // Q fragments: lo = rows q0..q0+15, hi = rows q0+16..q0+31
    short8_t qlo[2], qhi[2];
    #pragma unroll
    for (int hs = 0; hs < 2; ++hs) {
        qlo[hs] = *reinterpret_cast<const short8_t*>(
            &qg[(rbase + q0 + l15) * H_DIM + hs * 32 + kof]);
        qhi[hs] = *reinterpret_cast<const short8_t*>(
            &qg[(rbase + q0 + 16 + l15) * H_DIM + hs * 32 + kof]);
    }

    f32x4 olo[4] = {}, ohi[4] = {};
    float mlo = -1e30f, mhi = -1e30f, llo = 0.f, lhi = 0.f;

    const unsigned short* kp = kg + (rbase + (size_t)wv * 64) * H_DIM
                             + (size_t)l15 * H_DIM + kof;       // lane-folded
    const unsigned short* vp = vt + vbase + (size_t)l15 * T_CTX + wv * 64 + kof;

    for (int kt = wv; kt < nkv; kt += 8) {
        const int k0 = kt * 64;

        // S^T for both q-halves; kf loaded once per hs
        f32x4 slo[4] = {}, shi[4] = {};
        #pragma unroll
        for (int hs = 0; hs < 2; ++hs) {
            short8_t kf[4];
            #pragma unroll
            for (int ct = 0; ct < 4; ++ct)
                kf[ct] = *reinterpret_cast<const short8_t*>(kp + ct * 16 * H_DIM + hs * 32);
            #pragma unroll
            for (int ct = 0; ct < 4; ++ct) {
                slo[ct] = __builtin_amdgcn_mfma_f32_16x16x32_bf16(kf[ct], qlo[hs], slo[ct], 0, 0, 0);
                shi[ct] = __builtin_amdgcn_mfma_f32_16x16x32_bf16(kf[ct], qhi[hs], shi[ct], 0, 0, 0);
            }
        }

        if (kt == nkv - 1) {   // only the last tile crosses the diagonal
            #pragma unroll
            for (int ct = 0; ct < 4; ++ct)
                #pragma unroll
                for (int r = 0; r < 4; ++r) {
                    const int kv = k0 + ct * 16 + lg * 4 + r;
                    if (kv > q0 + l15)      slo[ct][r] = -1e30f;
                    if (kv > q0 + 16 + l15) shi[ct][r] = -1e30f;
                }
        }

        // row maxima (lane owns rows l15 / 16+l15)
        float mxlo, mxhi;
        {
            float a = fmaxf(fmaxf(slo[0][0], slo[0][1]), fmaxf(slo[0][2], slo[0][3]));
            float b = fmaxf(fmaxf(slo[1][0], slo[1][1]), fmaxf(slo[1][2], slo[1][3]));
            float c = fmaxf(fmaxf(slo[2][0], slo[2][1]), fmaxf(slo[2][2], slo[2][3]));
            float d = fmaxf(fmaxf(slo[3][0], slo[3][1]), fmaxf(slo[3][2], slo[3][3]));
            mxlo = fmaxf(fmaxf(a, b), fmaxf(c, d));
            a = fmaxf(fmaxf(shi[0][0], shi[0][1]), fmaxf(shi[0][2], shi[0][3]));
            b = fmaxf(fmaxf(shi[1][0], shi[1][1]), fmaxf(shi[1][2], shi[1][3]));
            c = fmaxf(fmaxf(shi[2][0], shi[2][1]), fmaxf(shi[2][2], shi[2][3]));
            d = fmaxf(fmaxf(shi[3][0], shi[3][1]), fmaxf(shi[3][2], shi[3][3]));
            mxhi = fmaxf(fmaxf(a, b), fmaxf(c, d));
        }
        mxlo = fmaxf(mxlo, __shfl_xor(mxlo, 16));
        mxlo = fmaxf(mxlo, __shfl_xor(mxlo, 32));
        mxhi = fmaxf(mxhi, __shfl_xor(mxhi, 16));
        mxhi = fmaxf(mxhi, __shfl_xor(mxhi, 32));

        // defer-max: skip rescale while growth stays under THR
        if (!__all((mxlo <= mlo + DEFER_THR) && (mxhi <= mhi + DEFER_THR))) {
            const float nmlo = fmaxf(mlo, mxlo), nmhi = fmaxf(mhi, mxhi);
            const float cflo = fexp2(mlo - nmlo), cfhi = fexp2(mhi - nmhi);
            llo *= cflo; lhi *= cfhi;
            mlo = nmlo; mhi = nmhi;
            #pragma unroll
            for (int r = 0; r < 4; ++r) {
                const float cl = __shfl(cflo, lg * 4 + r);
                const float ch = __shfl(cfhi, lg * 4 + r);
                #pragma unroll
                for (int oc = 0; oc < 4; ++oc) { olo[oc][r] *= cl; ohi[oc][r] *= ch; }
            }
        }

        // P = exp2(S - m), write to per-wave LDS tile
        float rllo = 0.f, rlhi = 0.f;
        #pragma unroll
        for (int ct = 0; ct < 4; ++ct) {
            const float p0 = fexp2(slo[ct][0] - mlo), p1 = fexp2(slo[ct][1] - mlo);
            const float p2 = fexp2(slo[ct][2] - mlo), p3 = fexp2(slo[ct][3] - mlo);
            rllo += (p0 + p1) + (p2 + p3);
            uint2 pw; pw.x = cvtpk(p0, p1); pw.y = cvtpk(p2, p3);
            *reinterpret_cast<uint2*>(&Pt[pbase + swz(l15, ct * 16 + lg * 4)]) = pw;
            const float h0 = fexp2(shi[ct][0] - mhi), h1 = fexp2(shi[ct][1] - mhi);
            const float h2 = fexp2(shi[ct][2] - mhi), h3 = fexp2(shi[ct][3] - mhi);
            rlhi += (h0 + h1) + (h2 + h3);
            uint2 ph; ph.x = cvtpk(h0, h1); ph.y = cvtpk(h2, h3);
            *reinterpret_cast<uint2*>(&Pt[pbase + swz(16 + l15, ct * 16 + lg * 4)]) = ph;
        }
        rllo += __shfl_xor(rllo, 16); rllo += __shfl_xor(rllo, 32);
        rlhi += __shfl_xor(rlhi, 16); rlhi += __shfl_xor(rlhi, 32);
        llo += rllo; lhi += rlhi;

        // O += P V, ks-sequenced (16 V regs live at a time)
        #pragma unroll
        for (int ks = 0; ks < 2; ++ks) {
            short8_t vf4[4];
            #pragma unroll
            for (int oc = 0; oc < 4; ++oc)
                vf4[oc] = *reinterpret_cast<const short8_t*>(
                    vp + (size_t)(oc * 16) * T_CTX + ks * 32);
            const short8_t palo = *reinterpret_cast<const short8_t*>(
                &Pt[pbase + swz(l15, ks * 32 + kof)]);
            const short8_t pahi = *reinterpret_cast<const short8_t*>(
                &Pt[pbase + swz(16 + l15, ks * 32 + kof)]);
            #pragma unroll
            for (int oc = 0; oc < 4; ++oc) {
                olo[oc] = __builtin_amdgcn_mfma_f32_16x16x32_bf16(palo, vf4[oc], olo[oc], 0, 0, 0);
                ohi[oc] = __builtin_amdgcn_mfma_f32_16x16x32_bf16(pahi, vf4[oc], ohi[oc], 0, 0, 0);
            }
        }

        kp += 8 * 64 * H_DIM;   // 8 tiles x 64 rows
        vp += 8 * 64;           // 8 tiles x 64 kv cols
    }

    // ---- two-phase flat LSE merge: phase 0 = lo rows, phase 1 = hi rows ----
    #pragma unroll
    for (int ph = 0; ph < 2; ++ph) {
        __syncthreads();   // Pt / previous-phase reads complete
        // publish: o region wv (16 rows x 64), m/l at 8192+/8320+
        #pragma unroll
        for (int oc = 0; oc < 4; ++oc)
            #pragma unroll
            for (int r = 0; r < 4; ++r)
                smem[wv * 1024 + (lg * 4 + r) * 64 + oc * 16 + l15] =
                    ph ? ohi[oc][r] : olo[oc][r];
        if (lg == 0) {
            smem[8192 + wv * 16 + l15] = ph ? mhi : mlo;
            smem[8320 + wv * 16 + l15] = ph ? lhi : llo;
        }
        __syncthreads();
        const int row = tid >> 5;          // 0..15
        const int c2  = (tid & 31) * 2;
        float M = -1e30f;
        #pragma unroll
        for (int w = 0; w < 8; ++w) M = fmaxf(M, smem[8192 + w * 16 + row]);
        float L = 0.f, a0 = 0.f, a1 = 0.f;
        #pragma unroll
        for (int w = 0; w < 8; ++w) {
            const float e = fexp2(smem[8192 + w * 16 + row] - M);
            L += e * smem[8320 + w * 16 + row];
            a0 += e * smem[w * 1024 + row * 64 + c2];
            a1 += e * smem[w * 1024 + row * 64 + c2 + 1];
        }
        const float inv = 1.0f / L;
        float2 rr; rr.x = a0 * inv; rr.y = a1 * inv;
        *reinterpret_cast<float2*>(
            &outp[(rbase + q0 + ph * 16 + row) * H_DIM + c2]) = rr;
    }
}

extern "C" void kernel_launch(void* const* d_in, const int* in_sizes, int n_in,
                              void* d_out, int out_size, void* d_ws, size_t ws_size,
                              hipStream_t stream) {
    const float* x  = (const float*)d_in[0];
    const float* Wq = (const float*)d_in[1];
    const float* bq = (const float*)d_in[2];
    const float* Wk = (const float*)d_in[3];
    const float* bk = (const float*)d_in[4];
    const float* Wv = (const float*)d_in[5];
    const float* bv = (const float*)d_in[6];
    float* out = (float*)d_out;

    // ws (ushort): Wt[3*64*1024] | q[16384*64] | k[16384*64] | vt[4*64*4096]
    unsigned short* wt  = (unsigned short*)d_ws;
    unsigned short* qb  = wt + 3 * H_DIM * E_DIM;
    unsigned short* kb  = qb + (size_t)M_ROWS * H_DIM;
    unsigned short* vtb = kb + (size_t)M_ROWS * H_DIM;

    prep_weights<<<dim3(E_DIM / 64, 3), 256, 0, stream>>>(Wq, Wk, Wv, wt);
    proj_kernel<<<dim3(M_ROWS / 16), 256, 0, stream>>>(x, wt, bq, bk, bv, qb, kb, vtb);
    attn_kernel<<<dim3((T_CTX / 32) * B_SZ), 512, 0, stream>>>(qb, kb, vtb, out);
}

// Round 9
// 99.502 us; speedup vs baseline: 1.8504x; 1.0105x over previous
//
#include <hip/hip_runtime.h>

typedef __attribute__((ext_vector_type(8))) short short8_t;
typedef __attribute__((ext_vector_type(4))) float f32x4;

namespace {
constexpr int T_CTX  = 4096;
constexpr int E_DIM  = 1024;
constexpr int H_DIM  = 64;
constexpr int B_SZ   = 4;
constexpr int M_ROWS = B_SZ * T_CTX; // 16384
// 1/sqrt(H) * log2(e): S lands in log2 domain -> softmax via exp2
constexpr float SCALE_Q = 0.125f * 1.4426950408889634f;
constexpr float DEFER_THR = 8.0f;    // log2 units; P bounded by 2^8
}

__device__ __forceinline__ unsigned short f2bf(float f) {
    unsigned u = __builtin_bit_cast(unsigned, f);
    u += 0x7fffu + ((u >> 16) & 1u);          // RNE
    return (unsigned short)(u >> 16);
}
__device__ __forceinline__ unsigned pack2(unsigned short lo, unsigned short hi) {
    return (unsigned)lo | ((unsigned)hi << 16);
}
__device__ __forceinline__ unsigned cvtpk(float lo, float hi) {
    unsigned r;
    asm("v_cvt_pk_bf16_f32 %0, %1, %2" : "=v"(r) : "v"(lo), "v"(hi));
    return r;
}
__device__ __forceinline__ float fexp2(float x) {   // guaranteed v_exp_f32
    float r;
    asm("v_exp_f32 %0, %1" : "=v"(r) : "v"(x));
    return r;
}
// swizzled ushort index into a row-major [rows][64] bf16 LDS tile
__device__ __forceinline__ int swz(int row, int col) {
    return row * 64 + (col ^ ((row & 7) << 3));
}

// ---------------------------------------------------------------------------
// Weight prep: W[1024][64] fp32 -> Wt[64][1024] bf16 (per matrix), via LDS.
// ---------------------------------------------------------------------------
__global__ __launch_bounds__(256)
void prep_weights(const float* __restrict__ Wq, const float* __restrict__ Wk,
                  const float* __restrict__ Wv, unsigned short* __restrict__ wt)
{
    const int mat = blockIdx.y;
    const float* W = (mat == 0) ? Wq : (mat == 1) ? Wk : Wv;
    unsigned short* out = wt + (size_t)mat * H_DIM * E_DIM;
    __shared__ float Ls[64][65];
    const int tid = threadIdx.x;
    const int kb = blockIdx.x * 64;
    #pragma unroll
    for (int j = 0; j < 4; ++j) {
        int p = j * 256 + tid;
        int kr = p >> 4, c4 = (p & 15) * 4;
        float4 w4 = *reinterpret_cast<const float4*>(&W[(size_t)(kb + kr) * H_DIM + c4]);
        Ls[c4 + 0][kr] = w4.x; Ls[c4 + 1][kr] = w4.y;
        Ls[c4 + 2][kr] = w4.z; Ls[c4 + 3][kr] = w4.w;
    }
    __syncthreads();
    #pragma unroll
    for (int j = 0; j < 2; ++j) {
        int p = j * 256 + tid;
        int n = p >> 3, c8 = (p & 7) * 8;
        uint4 w;
        w.x = pack2(f2bf(Ls[n][c8 + 0]), f2bf(Ls[n][c8 + 1]));
        w.y = pack2(f2bf(Ls[n][c8 + 2]), f2bf(Ls[n][c8 + 3]));
        w.z = pack2(f2bf(Ls[n][c8 + 4]), f2bf(Ls[n][c8 + 5]));
        w.w = pack2(f2bf(Ls[n][c8 + 6]), f2bf(Ls[n][c8 + 7]));
        *reinterpret_cast<uint4*>(&out[(size_t)n * E_DIM + kb + c8]) = w;
    }
}

// ---------------------------------------------------------------------------
// Fused QKV projection. Block = 64 rows x 512 thr = 8 waves:
// wave = (rg 0..3 = 16-row group, kh 0..1 = K-half of 512).
// Barrier-free streaming K-loop with 2-deep x prefetch; grouped b-loads
// (L1-shared across the 4 same-kh waves). One-barrier LDS k-half merge;
// per-rg-wave staged coalesced epilogue via a DEDICATED ushort buffer
// (round-8 bug: staging aliased the fp32 merge buffer -> compiler reorder).
// ---------------------------------------------------------------------------
__global__ __launch_bounds__(512)
void proj_kernel(const float* __restrict__ x, const unsigned short* __restrict__ wt,
                 const float* __restrict__ bq, const float* __restrict__ bk,
                 const float* __restrict__ bv,
                 unsigned short* __restrict__ qb, unsigned short* __restrict__ kb,
                 unsigned short* __restrict__ vtb)
{
    const int tid = threadIdx.x;
    const int lane = tid & 63, wv = tid >> 6;   // wv 0..7
    const int l15 = lane & 15, lg = lane >> 4;
    const int kof = lg * 8;

    const int rg = wv & 3;                      // row-group
    const int kh = wv >> 2;                     // k-half
    const int m0    = blockIdx.x * 64 + rg * 16;
    const int batch = m0 >> 12;
    const int t0    = m0 & (T_CTX - 1);
    const int kbeg  = kh * 512;

    f32x4 acc[3][4] = {};
    const float* xrow = &x[(size_t)(m0 + l15) * E_DIM + kof];

    // 2-deep x prefetch (named rotation)
    float4 xa0 = *reinterpret_cast<const float4*>(xrow + kbeg);
    float4 xb0 = *reinterpret_cast<const float4*>(xrow + kbeg + 4);
    float4 xa1 = *reinterpret_cast<const float4*>(xrow + kbeg + 32);
    float4 xb1 = *reinterpret_cast<const float4*>(xrow + kbeg + 36);

    for (int k0 = kbeg; k0 < kbeg + 512; k0 += 32) {
        const int kn = (k0 + 64 < kbeg + 512) ? k0 + 64 : kbeg;
        float4 na = *reinterpret_cast<const float4*>(xrow + kn);
        float4 nb = *reinterpret_cast<const float4*>(xrow + kn + 4);

        // grouped b-loads (12 in flight; identical addrs across same-kh waves)
        short8_t bf[12];
        #pragma unroll
        for (int mat = 0; mat < 3; ++mat)
            #pragma unroll
            for (int oc = 0; oc < 4; ++oc)
                bf[mat * 4 + oc] = *reinterpret_cast<const short8_t*>(
                    &wt[((size_t)mat * H_DIM + oc * 16 + l15) * E_DIM + k0 + kof]);

        uint4 au;
        au.x = cvtpk(xa0.x, xa0.y); au.y = cvtpk(xa0.z, xa0.w);
        au.z = cvtpk(xb0.x, xb0.y); au.w = cvtpk(xb0.z, xb0.w);
        const short8_t a = __builtin_bit_cast(short8_t, au);

        #pragma unroll
        for (int mat = 0; mat < 3; ++mat)
            #pragma unroll
            for (int oc = 0; oc < 4; ++oc)
                acc[mat][oc] = __builtin_amdgcn_mfma_f32_16x16x32_bf16(
                    a, bf[mat * 4 + oc], acc[mat][oc], 0, 0, 0);

        xa0 = xa1; xb0 = xb1; xa1 = na; xb1 = nb;
    }

    // ---- k-half merge: kh=1 dumps, kh=0 adds ----
    __shared__ float Ms[4][64][49];              // 50 KB fp32 merge
    __shared__ unsigned short Stg[4][1024];      // 8 KB bf16 staging (NO alias)
    if (kh == 1) {
        #pragma unroll
        for (int mat = 0; mat < 3; ++mat)
            #pragma unroll
            for (int oc = 0; oc < 4; ++oc)
                #pragma unroll
                for (int r = 0; r < 4; ++r)
                    Ms[rg][lane][(mat * 4 + oc) * 4 + r] = acc[mat][oc][r];
    }
    __syncthreads();
    if (kh == 0) {
        #pragma unroll
        for (int mat = 0; mat < 3; ++mat)
            #pragma unroll
            for (int oc = 0; oc < 4; ++oc)
                #pragma unroll
                for (int r = 0; r < 4; ++r)
                    acc[mat][oc][r] += Ms[rg][lane][(mat * 4 + oc) * 4 + r];

        // per-rg epilogue; dedicated buffer; same-wave LDS ordering is in-order
        unsigned short* stage = &Stg[rg][0];

        #pragma unroll
        for (int mat = 0; mat < 2; ++mat) {
            const float* bias = mat ? bk : bq;
            const float sc = mat ? 1.0f : SCALE_Q;
            #pragma unroll
            for (int oc = 0; oc < 4; ++oc) {
                const float bb = bias[oc * 16 + l15];
                #pragma unroll
                for (int r = 0; r < 4; ++r)
                    stage[swz(lg * 4 + r, oc * 16 + l15)] =
                        f2bf((acc[mat][oc][r] + bb) * sc);
            }
            unsigned short* outg = mat ? kb : qb;
            const int row = lane >> 2, c = (lane & 3) * 16;
            uint4 w0 = *reinterpret_cast<const uint4*>(&stage[swz(row, c)]);
            uint4 w1 = *reinterpret_cast<const uint4*>(&stage[swz(row, c + 8)]);
            *reinterpret_cast<uint4*>(&outg[(size_t)(m0 + row) * H_DIM + c]) = w0;
            *reinterpret_cast<uint4*>(&outg[(size_t)(m0 + row) * H_DIM + c + 8]) = w1;
        }

        #pragma unroll
        for (int oc = 0; oc < 4; ++oc) {
            const float bb = bv[oc * 16 + l15];
            const int h = oc * 16 + l15;
            uint2 pw;
            pw.x = cvtpk(acc[2][oc][0] + bb, acc[2][oc][1] + bb);
            pw.y = cvtpk(acc[2][oc][2] + bb, acc[2][oc][3] + bb);
            *reinterpret_cast<uint2*>(&stage[h * 16 + lg * 4]) = pw;
        }
        const int h = lane;
        uint4 v0 = *reinterpret_cast<const uint4*>(&stage[h * 16]);
        uint4 v1 = *reinterpret_cast<const uint4*>(&stage[h * 16 + 8]);
        unsigned short* vrow = &vtb[((size_t)batch * H_DIM + h) * T_CTX + t0];
        *reinterpret_cast<uint4*>(&vrow[0]) = v0;
        *reinterpret_cast<uint4*>(&vrow[8]) = v1;
    }
}

// ---------------------------------------------------------------------------
// Causal flash attention: 32 q-rows per wave, 8-way split-KV per block.
// Block = (32-row strip, batch), 512 thr. Swapped QK^T (lane owns q-rows
// l15 and 16+l15), defer-max, exp2 domain, v_exp asm. End: two-phase flat
// LSE merge (lo rows, hi rows) in aliased 33KB LDS.
// ---------------------------------------------------------------------------
__global__ __launch_bounds__(512)
void attn_kernel(const unsigned short* __restrict__ qg,
                 const unsigned short* __restrict__ kg,
                 const unsigned short* __restrict__ vt,
                 float* __restrict__ outp)
{
    const int tid  = threadIdx.x;
    const int lane = tid & 63, wv = tid >> 6;   // wv 0..7
    const int l15 = lane & 15, lg = lane >> 4;
    const int kof = lg * 8;

    const int idx   = 511 - blockIdx.x;         // heavy strips first
    const int st    = idx >> 2;                 // 0..127 (32-row strips)
    const int batch = idx & 3;
    const int q0    = st * 32;
    const int nkv   = st / 2 + 1;               // 64-wide kv tiles
    const size_t rbase = (size_t)batch * T_CTX;
    const size_t vbase = (size_t)batch * H_DIM * T_CTX;

    __shared__ float smem[8448];                // Pt (32KB) ∪ merge (33KB)
    unsigned short* Pt = (unsigned short*)smem;
    const int pbase = wv * 2048;                // per-wave [32][64] bf16

    // Q fragments: lo = rows q0..q0+15, hi = rows q0+16..q0+31
    short8_t qlo[2], qhi[2];
    #pragma unroll
    for (int hs = 0; hs < 2; ++hs) {
        qlo[hs] = *reinterpret_cast<const short8_t*>(
            &qg[(rbase + q0 + l15) * H_DIM + hs * 32 + kof]);
        qhi[hs] = *reinterpret_cast<const short8_t*>(
            &qg[(rbase + q0 + 16 + l15) * H_DIM + hs * 32 + kof]);
    }

    f32x4 olo[4] = {}, ohi[4] = {};
    float mlo = -1e30f, mhi = -1e30f, llo = 0.f, lhi = 0.f;

    const unsigned short* kp = kg + (rbase + (size_t)wv * 64) * H_DIM
                             + (size_t)l15 * H_DIM + kof;       // lane-folded
    const unsigned short* vp = vt + vbase + (size_t)l15 * T_CTX + wv * 64 + kof;

    for (int kt = wv; kt < nkv; kt += 8) {
        const int k0 = kt * 64;

        // S^T for both q-halves; kf loaded once per hs
        f32x4 slo[4] = {}, shi[4] = {};
        #pragma unroll
        for (int hs = 0; hs < 2; ++hs) {
            short8_t kf[4];
            #pragma unroll
            for (int ct = 0; ct < 4; ++ct)
                kf[ct] = *reinterpret_cast<const short8_t*>(kp + ct * 16 * H_DIM + hs * 32);
            #pragma unroll
            for (int ct = 0; ct < 4; ++ct) {
                slo[ct] = __builtin_amdgcn_mfma_f32_16x16x32_bf16(kf[ct], qlo[hs], slo[ct], 0, 0, 0);
                shi[ct] = __builtin_amdgcn_mfma_f32_16x16x32_bf16(kf[ct], qhi[hs], shi[ct], 0, 0, 0);
            }
        }

        if (kt == nkv - 1) {   // only the last tile crosses the diagonal
            #pragma unroll
            for (int ct = 0; ct < 4; ++ct)
                #pragma unroll
                for (int r = 0; r < 4; ++r) {
                    const int kv = k0 + ct * 16 + lg * 4 + r;
                    if (kv > q0 + l15)      slo[ct][r] = -1e30f;
                    if (kv > q0 + 16 + l15) shi[ct][r] = -1e30f;
                }
        }

        // row maxima (lane owns rows l15 / 16+l15)
        float mxlo, mxhi;
        {
            float a = fmaxf(fmaxf(slo[0][0], slo[0][1]), fmaxf(slo[0][2], slo[0][3]));
            float b = fmaxf(fmaxf(slo[1][0], slo[1][1]), fmaxf(slo[1][2], slo[1][3]));
            float c = fmaxf(fmaxf(slo[2][0], slo[2][1]), fmaxf(slo[2][2], slo[2][3]));
            float d = fmaxf(fmaxf(slo[3][0], slo[3][1]), fmaxf(slo[3][2], slo[3][3]));
            mxlo = fmaxf(fmaxf(a, b), fmaxf(c, d));
            a = fmaxf(fmaxf(shi[0][0], shi[0][1]), fmaxf(shi[0][2], shi[0][3]));
            b = fmaxf(fmaxf(shi[1][0], shi[1][1]), fmaxf(shi[1][2], shi[1][3]));
            c = fmaxf(fmaxf(shi[2][0], shi[2][1]), fmaxf(shi[2][2], shi[2][3]));
            d = fmaxf(fmaxf(shi[3][0], shi[3][1]), fmaxf(shi[3][2], shi[3][3]));
            mxhi = fmaxf(fmaxf(a, b), fmaxf(c, d));
        }
        mxlo = fmaxf(mxlo, __shfl_xor(mxlo, 16));
        mxlo = fmaxf(mxlo, __shfl_xor(mxlo, 32));
        mxhi = fmaxf(mxhi, __shfl_xor(mxhi, 16));
        mxhi = fmaxf(mxhi, __shfl_xor(mxhi, 32));

        // defer-max: skip rescale while growth stays under THR
        if (!__all((mxlo <= mlo + DEFER_THR) && (mxhi <= mhi + DEFER_THR))) {
            const float nmlo = fmaxf(mlo, mxlo), nmhi = fmaxf(mhi, mxhi);
            const float cflo = fexp2(mlo - nmlo), cfhi = fexp2(mhi - nmhi);
            llo *= cflo; lhi *= cfhi;
            mlo = nmlo; mhi = nmhi;
            #pragma unroll
            for (int r = 0; r < 4; ++r) {
                const float cl = __shfl(cflo, lg * 4 + r);
                const float ch = __shfl(cfhi, lg * 4 + r);
                #pragma unroll
                for (int oc = 0; oc < 4; ++oc) { olo[oc][r] *= cl; ohi[oc][r] *= ch; }
            }
        }

        // P = exp2(S - m), write to per-wave LDS tile
        float rllo = 0.f, rlhi = 0.f;
        #pragma unroll
        for (int ct = 0; ct < 4; ++ct) {
            const float p0 = fexp2(slo[ct][0] - mlo), p1 = fexp2(slo[ct][1] - mlo);
            const float p2 = fexp2(slo[ct][2] - mlo), p3 = fexp2(slo[ct][3] - mlo);
            rllo += (p0 + p1) + (p2 + p3);
            uint2 pw; pw.x = cvtpk(p0, p1); pw.y = cvtpk(p2, p3);
            *reinterpret_cast<uint2*>(&Pt[pbase + swz(l15, ct * 16 + lg * 4)]) = pw;
            const float h0 = fexp2(shi[ct][0] - mhi), h1 = fexp2(shi[ct][1] - mhi);
            const float h2 = fexp2(shi[ct][2] - mhi), h3 = fexp2(shi[ct][3] - mhi);
            rlhi += (h0 + h1) + (h2 + h3);
            uint2 ph; ph.x = cvtpk(h0, h1); ph.y = cvtpk(h2, h3);
            *reinterpret_cast<uint2*>(&Pt[pbase + swz(16 + l15, ct * 16 + lg * 4)]) = ph;
        }
        rllo += __shfl_xor(rllo, 16); rllo += __shfl_xor(rllo, 32);
        rlhi += __shfl_xor(rlhi, 16); rlhi += __shfl_xor(rlhi, 32);
        llo += rllo; lhi += rlhi;

        // O += P V, ks-sequenced (16 V regs live at a time)
        #pragma unroll
        for (int ks = 0; ks < 2; ++ks) {
            short8_t vf4[4];
            #pragma unroll
            for (int oc = 0; oc < 4; ++oc)
                vf4[oc] = *reinterpret_cast<const short8_t*>(
                    vp + (size_t)(oc * 16) * T_CTX + ks * 32);
            const short8_t palo = *reinterpret_cast<const short8_t*>(
                &Pt[pbase + swz(l15, ks * 32 + kof)]);
            const short8_t pahi = *reinterpret_cast<const short8_t*>(
                &Pt[pbase + swz(16 + l15, ks * 32 + kof)]);
            #pragma unroll
            for (int oc = 0; oc < 4; ++oc) {
                olo[oc] = __builtin_amdgcn_mfma_f32_16x16x32_bf16(palo, vf4[oc], olo[oc], 0, 0, 0);
                ohi[oc] = __builtin_amdgcn_mfma_f32_16x16x32_bf16(pahi, vf4[oc], ohi[oc], 0, 0, 0);
            }
        }

        kp += 8 * 64 * H_DIM;   // 8 tiles x 64 rows
        vp += 8 * 64;           // 8 tiles x 64 kv cols
    }

    // ---- two-phase flat LSE merge: phase 0 = lo rows, phase 1 = hi rows ----
    #pragma unroll
    for (int ph = 0; ph < 2; ++ph) {
        __syncthreads();   // Pt / previous-phase reads complete
        // publish: o region wv (16 rows x 64), m/l at 8192+/8320+
        #pragma unroll
        for (int oc = 0; oc < 4; ++oc)
            #pragma unroll
            for (int r = 0; r < 4; ++r)
                smem[wv * 1024 + (lg * 4 + r) * 64 + oc * 16 + l15] =
                    ph ? ohi[oc][r] : olo[oc][r];
        if (lg == 0) {
            smem[8192 + wv * 16 + l15] = ph ? mhi : mlo;
            smem[8320 + wv * 16 + l15] = ph ? lhi : llo;
        }
        __syncthreads();
        const int row = tid >> 5;          // 0..15
        const int c2  = (tid & 31) * 2;
        float M = -1e30f;
        #pragma unroll
        for (int w = 0; w < 8; ++w) M = fmaxf(M, smem[8192 + w * 16 + row]);
        float L = 0.f, a0 = 0.f, a1 = 0.f;
        #pragma unroll
        for (int w = 0; w < 8; ++w) {
            const float e = fexp2(smem[8192 + w * 16 + row] - M);
            L += e * smem[8320 + w * 16 + row];
            a0 += e * smem[w * 1024 + row * 64 + c2];
            a1 += e * smem[w * 1024 + row * 64 + c2 + 1];
        }
        const float inv = 1.0f / L;
        float2 rr; rr.x = a0 * inv; rr.y = a1 * inv;
        *reinterpret_cast<float2*>(
            &outp[(rbase + q0 + ph * 16 + row) * H_DIM + c2]) = rr;
    }
}

extern "C" void kernel_launch(void* const* d_in, const int* in_sizes, int n_in,
                              void* d_out, int out_size, void* d_ws, size_t ws_size,
                              hipStream_t stream) {
    const float* x  = (const float*)d_in[0];
    const float* Wq = (const float*)d_in[1];
    const float* bq = (const float*)d_in[2];
    const float* Wk = (const float*)d_in[3];
    const float* bk = (const float*)d_in[4];
    const float* Wv = (const float*)d_in[5];
    const float* bv = (const float*)d_in[6];
    float* out = (float*)d_out;

    // ws (ushort): Wt[3*64*1024] | q[16384*64] | k[16384*64] | vt[4*64*4096]
    unsigned short* wt  = (unsigned short*)d_ws;
    unsigned short* qb  = wt + 3 * H_DIM * E_DIM;
    unsigned short* kb  = qb + (size_t)M_ROWS * H_DIM;
    unsigned short* vtb = kb + (size_t)M_ROWS * H_DIM;

    prep_weights<<<dim3(E_DIM / 64, 3), 256, 0, stream>>>(Wq, Wk, Wv, wt);
    proj_kernel<<<dim3(M_ROWS / 64), 512, 0, stream>>>(x, wt, bq, bk, bv, qb, kb, vtb);
    attn_kernel<<<dim3((T_CTX / 32) * B_SZ), 512, 0, stream>>>(qb, kb, vtb, out);
}

// Round 10
// 69.030 us; speedup vs baseline: 2.6673x; 1.4414x over previous
//
#include <hip/hip_runtime.h>

typedef __attribute__((ext_vector_type(8))) short short8_t;
typedef __attribute__((ext_vector_type(4))) float f32x4;

namespace {
constexpr int T_CTX  = 4096;
constexpr int E_DIM  = 1024;
constexpr int H_DIM  = 64;
constexpr int B_SZ   = 4;
constexpr int M_ROWS = B_SZ * T_CTX; // 16384
// 1/sqrt(H) * log2(e): S lands in log2 domain -> softmax via exp2
constexpr float SCALE_Q = 0.125f * 1.4426950408889634f;
constexpr float DEFER_THR = 8.0f;    // log2 units; P bounded by 2^8
}

__device__ __forceinline__ unsigned short f2bf(float f) {
    unsigned u = __builtin_bit_cast(unsigned, f);
    u += 0x7fffu + ((u >> 16) & 1u);          // RNE
    return (unsigned short)(u >> 16);
}
__device__ __forceinline__ unsigned pack2(unsigned short lo, unsigned short hi) {
    return (unsigned)lo | ((unsigned)hi << 16);
}
__device__ __forceinline__ unsigned cvtpk(float lo, float hi) {
    unsigned r;
    asm("v_cvt_pk_bf16_f32 %0, %1, %2" : "=v"(r) : "v"(lo), "v"(hi));
    return r;
}
__device__ __forceinline__ float fexp2(float x) {   // guaranteed v_exp_f32
    float r;
    asm("v_exp_f32 %0, %1" : "=v"(r) : "v"(x));
    return r;
}
// swizzled ushort index into a row-major [rows][64] bf16 LDS tile
__device__ __forceinline__ int swz(int row, int col) {
    return row * 64 + (col ^ ((row & 7) << 3));
}

// ---------------------------------------------------------------------------
// Weight prep: W[1024][64] fp32 -> FRAGMENT-MAJOR bf16 layout:
// wt[((kc*24 + mat*8 + oc*2 + hs)*64 + lane)*8] = W[kc*64 + hs*32 + (lane>>4)*8 + i]
//                                                  [oc*16 + (lane&15)]
// so proj's b-load (mat,oc,hs) is one contiguous 64-lane x 16B = 1KB stream.
// Block = (kc, mat).
// ---------------------------------------------------------------------------
__global__ __launch_bounds__(256)
void prep_weights(const float* __restrict__ Wq, const float* __restrict__ Wk,
                  const float* __restrict__ Wv, unsigned short* __restrict__ wt)
{
    const int mat = blockIdx.y;
    const int kc  = blockIdx.x;
    const float* W = (mat == 0) ? Wq : (mat == 1) ? Wk : Wv;
    __shared__ float Ls[64][65];   // Ls[n][k_local]
    const int tid = threadIdx.x;
    const int kb = kc * 64;
    #pragma unroll
    for (int j = 0; j < 4; ++j) {
        int p = j * 256 + tid;
        int kr = p >> 4, c4 = (p & 15) * 4;
        float4 w4 = *reinterpret_cast<const float4*>(&W[(size_t)(kb + kr) * H_DIM + c4]);
        Ls[c4 + 0][kr] = w4.x; Ls[c4 + 1][kr] = w4.y;
        Ls[c4 + 2][kr] = w4.z; Ls[c4 + 3][kr] = w4.w;
    }
    __syncthreads();
    #pragma unroll
    for (int j = 0; j < 2; ++j) {
        int p = j * 256 + tid;       // 0..511
        int f  = p >> 6;             // 0..7 = oc*2 + hs
        int ln = p & 63;
        int n   = (f >> 1) * 16 + (ln & 15);
        int kb8 = (f & 1) * 32 + (ln >> 4) * 8;
        uint4 w;
        w.x = pack2(f2bf(Ls[n][kb8 + 0]), f2bf(Ls[n][kb8 + 1]));
        w.y = pack2(f2bf(Ls[n][kb8 + 2]), f2bf(Ls[n][kb8 + 3]));
        w.z = pack2(f2bf(Ls[n][kb8 + 4]), f2bf(Ls[n][kb8 + 5]));
        w.w = pack2(f2bf(Ls[n][kb8 + 6]), f2bf(Ls[n][kb8 + 7]));
        size_t off = ((size_t)(kc * 24 + mat * 8 + f) * 64 + ln) * 8;
        *reinterpret_cast<uint4*>(&wt[off]) = w;
    }
}

// ---------------------------------------------------------------------------
// Fused QKV projection. Block = 64 rows x 512 thr = 8 waves:
// wave = (rg 0..3 = 16-row group, kh 0..1 = K-half of 512).
// Streaming K-loop: fragment-major 1KB b-loads + 2-deep x prefetch.
// __launch_bounds__(512,1): let the allocator keep all 12 b-frags + acc
// register-resident (r9: self-capped VGPR=52 serialized the loads).
// One-barrier LDS k-half merge; dedicated bf16 staging buffer (r8 lesson).
// ---------------------------------------------------------------------------
__global__ __launch_bounds__(512, 1)
void proj_kernel(const float* __restrict__ x, const unsigned short* __restrict__ wt,
                 const float* __restrict__ bq, const float* __restrict__ bk,
                 const float* __restrict__ bv,
                 unsigned short* __restrict__ qb, unsigned short* __restrict__ kb,
                 unsigned short* __restrict__ vtb)
{
    const int tid = threadIdx.x;
    const int lane = tid & 63, wv = tid >> 6;   // wv 0..7
    const int l15 = lane & 15, lg = lane >> 4;
    const int kof = lg * 8;

    const int rg = wv & 3;                      // row-group
    const int kh = wv >> 2;                     // k-half
    const int m0    = blockIdx.x * 64 + rg * 16;
    const int batch = m0 >> 12;
    const int t0    = m0 & (T_CTX - 1);
    const int kbeg  = kh * 512;

    f32x4 acc[3][4] = {};
    const float* xrow = &x[(size_t)(m0 + l15) * E_DIM + kof];
    const unsigned short* wlane = wt + (size_t)lane * 8;   // lane-folded

    // 2-deep x prefetch (named rotation)
    float4 xa0 = *reinterpret_cast<const float4*>(xrow + kbeg);
    float4 xb0 = *reinterpret_cast<const float4*>(xrow + kbeg + 4);
    float4 xa1 = *reinterpret_cast<const float4*>(xrow + kbeg + 32);
    float4 xb1 = *reinterpret_cast<const float4*>(xrow + kbeg + 36);

    for (int k0 = kbeg; k0 < kbeg + 512; k0 += 32) {
        const int kn = (k0 + 64 < kbeg + 512) ? k0 + 64 : kbeg;
        float4 na = *reinterpret_cast<const float4*>(xrow + kn);
        float4 nb = *reinterpret_cast<const float4*>(xrow + kn + 4);

        // fragment-major b-loads: each = contiguous 64x16B, monotone addresses
        const int fb = (k0 >> 6) * 24 + ((k0 >> 5) & 1);
        short8_t bf[12];
        #pragma unroll
        for (int mat = 0; mat < 3; ++mat)
            #pragma unroll
            for (int oc = 0; oc < 4; ++oc)
                bf[mat * 4 + oc] = *reinterpret_cast<const short8_t*>(
                    wlane + (size_t)(fb + mat * 8 + oc * 2) * 512);

        uint4 au;
        au.x = cvtpk(xa0.x, xa0.y); au.y = cvtpk(xa0.z, xa0.w);
        au.z = cvtpk(xb0.x, xb0.y); au.w = cvtpk(xb0.z, xb0.w);
        const short8_t a = __builtin_bit_cast(short8_t, au);

        #pragma unroll
        for (int mat = 0; mat < 3; ++mat)
            #pragma unroll
            for (int oc = 0; oc < 4; ++oc)
                acc[mat][oc] = __builtin_amdgcn_mfma_f32_16x16x32_bf16(
                    a, bf[mat * 4 + oc], acc[mat][oc], 0, 0, 0);

        xa0 = xa1; xb0 = xb1; xa1 = na; xb1 = nb;
    }

    // ---- k-half merge: kh=1 dumps, kh=0 adds ----
    __shared__ float Ms[4][64][49];              // 50 KB fp32 merge
    __shared__ unsigned short Stg[4][1024];      // 8 KB bf16 staging (NO alias)
    if (kh == 1) {
        #pragma unroll
        for (int mat = 0; mat < 3; ++mat)
            #pragma unroll
            for (int oc = 0; oc < 4; ++oc)
                #pragma unroll
                for (int r = 0; r < 4; ++r)
                    Ms[rg][lane][(mat * 4 + oc) * 4 + r] = acc[mat][oc][r];
    }
    __syncthreads();
    if (kh == 0) {
        #pragma unroll
        for (int mat = 0; mat < 3; ++mat)
            #pragma unroll
            for (int oc = 0; oc < 4; ++oc)
                #pragma unroll
                for (int r = 0; r < 4; ++r)
                    acc[mat][oc][r] += Ms[rg][lane][(mat * 4 + oc) * 4 + r];

        // per-rg epilogue; dedicated buffer; same-wave LDS ordering is in-order
        unsigned short* stage = &Stg[rg][0];

        #pragma unroll
        for (int mat = 0; mat < 2; ++mat) {
            const float* bias = mat ? bk : bq;
            const float sc = mat ? 1.0f : SCALE_Q;
            #pragma unroll
            for (int oc = 0; oc < 4; ++oc) {
                const float bb = bias[oc * 16 + l15];
                #pragma unroll
                for (int r = 0; r < 4; ++r)
                    stage[swz(lg * 4 + r, oc * 16 + l15)] =
                        f2bf((acc[mat][oc][r] + bb) * sc);
            }
            unsigned short* outg = mat ? kb : qb;
            const int row = lane >> 2, c = (lane & 3) * 16;
            uint4 w0 = *reinterpret_cast<const uint4*>(&stage[swz(row, c)]);
            uint4 w1 = *reinterpret_cast<const uint4*>(&stage[swz(row, c + 8)]);
            *reinterpret_cast<uint4*>(&outg[(size_t)(m0 + row) * H_DIM + c]) = w0;
            *reinterpret_cast<uint4*>(&outg[(size_t)(m0 + row) * H_DIM + c + 8]) = w1;
        }

        #pragma unroll
        for (int oc = 0; oc < 4; ++oc) {
            const float bb = bv[oc * 16 + l15];
            const int h = oc * 16 + l15;
            uint2 pw;
            pw.x = cvtpk(acc[2][oc][0] + bb, acc[2][oc][1] + bb);
            pw.y = cvtpk(acc[2][oc][2] + bb, acc[2][oc][3] + bb);
            *reinterpret_cast<uint2*>(&stage[h * 16 + lg * 4]) = pw;
        }
        const int h = lane;
        uint4 v0 = *reinterpret_cast<const uint4*>(&stage[h * 16]);
        uint4 v1 = *reinterpret_cast<const uint4*>(&stage[h * 16 + 8]);
        unsigned short* vrow = &vtb[((size_t)batch * H_DIM + h) * T_CTX + t0];
        *reinterpret_cast<uint4*>(&vrow[0]) = v0;
        *reinterpret_cast<uint4*>(&vrow[8]) = v1;
    }
}

// ---------------------------------------------------------------------------
// Causal flash attention: 32 q-rows per wave, 8-way split-KV per block.
// Block = (32-row strip, batch), 512 thr. Swapped QK^T (lane owns q-rows
// l15 and 16+l15), defer-max, exp2 domain, v_exp asm. End: two-phase flat
// LSE merge (lo rows, hi rows) in aliased 33KB LDS.
// ---------------------------------------------------------------------------
__global__ __launch_bounds__(512)
void attn_kernel(const unsigned short* __restrict__ qg,
                 const unsigned short* __restrict__ kg,
                 const unsigned short* __restrict__ vt,
                 float* __restrict__ outp)
{
    const int tid  = threadIdx.x;
    const int lane = tid & 63, wv = tid >> 6;   // wv 0..7
    const int l15 = lane & 15, lg = lane >> 4;
    const int kof = lg * 8;

    const int idx   = 511 - blockIdx.x;         // heavy strips first
    const int st    = idx >> 2;                 // 0..127 (32-row strips)
    const int batch = idx & 3;
    const int q0    = st * 32;
    const int nkv   = st / 2 + 1;               // 64-wide kv tiles
    const size_t rbase = (size_t)batch * T_CTX;
    const size_t vbase = (size_t)batch * H_DIM * T_CTX;

    __shared__ float smem[8448];                // Pt (32KB) ∪ merge (33KB)
    unsigned short* Pt = (unsigned short*)smem;
    const int pbase = wv * 2048;                // per-wave [32][64] bf16

    // Q fragments: lo = rows q0..q0+15, hi = rows q0+16..q0+31
    short8_t qlo[2], qhi[2];
    #pragma unroll
    for (int hs = 0; hs < 2; ++hs) {
        qlo[hs] = *reinterpret_cast<const short8_t*>(
            &qg[(rbase + q0 + l15) * H_DIM + hs * 32 + kof]);
        qhi[hs] = *reinterpret_cast<const short8_t*>(
            &qg[(rbase + q0 + 16 + l15) * H_DIM + hs * 32 + kof]);
    }

    f32x4 olo[4] = {}, ohi[4] = {};
    float mlo = -1e30f, mhi = -1e30f, llo = 0.f, lhi = 0.f;

    const unsigned short* kp = kg + (rbase + (size_t)wv * 64) * H_DIM
                             + (size_t)l15 * H_DIM + kof;       // lane-folded
    const unsigned short* vp = vt + vbase + (size_t)l15 * T_CTX + wv * 64 + kof;

    for (int kt = wv; kt < nkv; kt += 8) {
        const int k0 = kt * 64;

        // S^T for both q-halves; kf loaded once per hs
        f32x4 slo[4] = {}, shi[4] = {};
        #pragma unroll
        for (int hs = 0; hs < 2; ++hs) {
            short8_t kf[4];
            #pragma unroll
            for (int ct = 0; ct < 4; ++ct)
                kf[ct] = *reinterpret_cast<const short8_t*>(kp + ct * 16 * H_DIM + hs * 32);
            #pragma unroll
            for (int ct = 0; ct < 4; ++ct) {
                slo[ct] = __builtin_amdgcn_mfma_f32_16x16x32_bf16(kf[ct], qlo[hs], slo[ct], 0, 0, 0);
                shi[ct] = __builtin_amdgcn_mfma_f32_16x16x32_bf16(kf[ct], qhi[hs], shi[ct], 0, 0, 0);
            }
        }

        if (kt == nkv - 1) {   // only the last tile crosses the diagonal
            #pragma unroll
            for (int ct = 0; ct < 4; ++ct)
                #pragma unroll
                for (int r = 0; r < 4; ++r) {
                    const int kv = k0 + ct * 16 + lg * 4 + r;
                    if (kv > q0 + l15)      slo[ct][r] = -1e30f;
                    if (kv > q0 + 16 + l15) shi[ct][r] = -1e30f;
                }
        }

        // row maxima (lane owns rows l15 / 16+l15)
        float mxlo, mxhi;
        {
            float a = fmaxf(fmaxf(slo[0][0], slo[0][1]), fmaxf(slo[0][2], slo[0][3]));
            float b = fmaxf(fmaxf(slo[1][0], slo[1][1]), fmaxf(slo[1][2], slo[1][3]));
            float c = fmaxf(fmaxf(slo[2][0], slo[2][1]), fmaxf(slo[2][2], slo[2][3]));
            float d = fmaxf(fmaxf(slo[3][0], slo[3][1]), fmaxf(slo[3][2], slo[3][3]));
            mxlo = fmaxf(fmaxf(a, b), fmaxf(c, d));
            a = fmaxf(fmaxf(shi[0][0], shi[0][1]), fmaxf(shi[0][2], shi[0][3]));
            b = fmaxf(fmaxf(shi[1][0], shi[1][1]), fmaxf(shi[1][2], shi[1][3]));
            c = fmaxf(fmaxf(shi[2][0], shi[2][1]), fmaxf(shi[2][2], shi[2][3]));
            d = fmaxf(fmaxf(shi[3][0], shi[3][1]), fmaxf(shi[3][2], shi[3][3]));
            mxhi = fmaxf(fmaxf(a, b), fmaxf(c, d));
        }
        mxlo = fmaxf(mxlo, __shfl_xor(mxlo, 16));
        mxlo = fmaxf(mxlo, __shfl_xor(mxlo, 32));
        mxhi = fmaxf(mxhi, __shfl_xor(mxhi, 16));
        mxhi = fmaxf(mxhi, __shfl_xor(mxhi, 32));

        // defer-max: skip rescale while growth stays under THR
        if (!__all((mxlo <= mlo + DEFER_THR) && (mxhi <= mhi + DEFER_THR))) {
            const float nmlo = fmaxf(mlo, mxlo), nmhi = fmaxf(mhi, mxhi);
            const float cflo = fexp2(mlo - nmlo), cfhi = fexp2(mhi - nmhi);
            llo *= cflo; lhi *= cfhi;
            mlo = nmlo; mhi = nmhi;
            #pragma unroll
            for (int r = 0; r < 4; ++r) {
                const float cl = __shfl(cflo, lg * 4 + r);
                const float ch = __shfl(cfhi, lg * 4 + r);
                #pragma unroll
                for (int oc = 0; oc < 4; ++oc) { olo[oc][r] *= cl; ohi[oc][r] *= ch; }
            }
        }

        // P = exp2(S - m), write to per-wave LDS tile
        float rllo = 0.f, rlhi = 0.f;
        #pragma unroll
        for (int ct = 0; ct < 4; ++ct) {
            const float p0 = fexp2(slo[ct][0] - mlo), p1 = fexp2(slo[ct][1] - mlo);
            const float p2 = fexp2(slo[ct][2] - mlo), p3 = fexp2(slo[ct][3] - mlo);
            rllo += (p0 + p1) + (p2 + p3);
            uint2 pw; pw.x = cvtpk(p0, p1); pw.y = cvtpk(p2, p3);
            *reinterpret_cast<uint2*>(&Pt[pbase + swz(l15, ct * 16 + lg * 4)]) = pw;
            const float h0 = fexp2(shi[ct][0] - mhi), h1 = fexp2(shi[ct][1] - mhi);
            const float h2 = fexp2(shi[ct][2] - mhi), h3 = fexp2(shi[ct][3] - mhi);
            rlhi += (h0 + h1) + (h2 + h3);
            uint2 ph; ph.x = cvtpk(h0, h1); ph.y = cvtpk(h2, h3);
            *reinterpret_cast<uint2*>(&Pt[pbase + swz(16 + l15, ct * 16 + lg * 4)]) = ph;
        }
        rllo += __shfl_xor(rllo, 16); rllo += __shfl_xor(rllo, 32);
        rlhi += __shfl_xor(rlhi, 16); rlhi += __shfl_xor(rlhi, 32);
        llo += rllo; lhi += rlhi;

        // O += P V, ks-sequenced (16 V regs live at a time)
        #pragma unroll
        for (int ks = 0; ks < 2; ++ks) {
            short8_t vf4[4];
            #pragma unroll
            for (int oc = 0; oc < 4; ++oc)
                vf4[oc] = *reinterpret_cast<const short8_t*>(
                    vp + (size_t)(oc * 16) * T_CTX + ks * 32);
            const short8_t palo = *reinterpret_cast<const short8_t*>(
                &Pt[pbase + swz(l15, ks * 32 + kof)]);
            const short8_t pahi = *reinterpret_cast<const short8_t*>(
                &Pt[pbase + swz(16 + l15, ks * 32 + kof)]);
            #pragma unroll
            for (int oc = 0; oc < 4; ++oc) {
                olo[oc] = __builtin_amdgcn_mfma_f32_16x16x32_bf16(palo, vf4[oc], olo[oc], 0, 0, 0);
                ohi[oc] = __builtin_amdgcn_mfma_f32_16x16x32_bf16(pahi, vf4[oc], ohi[oc], 0, 0, 0);
            }
        }

        kp += 8 * 64 * H_DIM;   // 8 tiles x 64 rows
        vp += 8 * 64;           // 8 tiles x 64 kv cols
    }

    // ---- two-phase flat LSE merge: phase 0 = lo rows, phase 1 = hi rows ----
    #pragma unroll
    for (int ph = 0; ph < 2; ++ph) {
        __syncthreads();   // Pt / previous-phase reads complete
        // publish: o region wv (16 rows x 64), m/l at 8192+/8320+
        #pragma unroll
        for (int oc = 0; oc < 4; ++oc)
            #pragma unroll
            for (int r = 0; r < 4; ++r)
                smem[wv * 1024 + (lg * 4 + r) * 64 + oc * 16 + l15] =
                    ph ? ohi[oc][r] : olo[oc][r];
        if (lg == 0) {
            smem[8192 + wv * 16 + l15] = ph ? mhi : mlo;
            smem[8320 + wv * 16 + l15] = ph ? lhi : llo;
        }
        __syncthreads();
        const int row = tid >> 5;          // 0..15
        const int c2  = (tid & 31) * 2;
        float M = -1e30f;
        #pragma unroll
        for (int w = 0; w < 8; ++w) M = fmaxf(M, smem[8192 + w * 16 + row]);
        float L = 0.f, a0 = 0.f, a1 = 0.f;
        #pragma unroll
        for (int w = 0; w < 8; ++w) {
            const float e = fexp2(smem[8192 + w * 16 + row] - M);
            L += e * smem[8320 + w * 16 + row];
            a0 += e * smem[w * 1024 + row * 64 + c2];
            a1 += e * smem[w * 1024 + row * 64 + c2 + 1];
        }
        const float inv = 1.0f / L;
        float2 rr; rr.x = a0 * inv; rr.y = a1 * inv;
        *reinterpret_cast<float2*>(
            &outp[(rbase + q0 + ph * 16 + row) * H_DIM + c2]) = rr;
    }
}

extern "C" void kernel_launch(void* const* d_in, const int* in_sizes, int n_in,
                              void* d_out, int out_size, void* d_ws, size_t ws_size,
                              hipStream_t stream) {
    const float* x  = (const float*)d_in[0];
    const float* Wq = (const float*)d_in[1];
    const float* bq = (const float*)d_in[2];
    const float* Wk = (const float*)d_in[3];
    const float* bk = (const float*)d_in[4];
    const float* Wv = (const float*)d_in[5];
    const float* bv = (const float*)d_in[6];
    float* out = (float*)d_out;

    // ws (ushort): Wt[3*64*1024] | q[16384*64] | k[16384*64] | vt[4*64*4096]
    unsigned short* wt  = (unsigned short*)d_ws;
    unsigned short* qb  = wt + 3 * H_DIM * E_DIM;
    unsigned short* kb  = qb + (size_t)M_ROWS * H_DIM;
    unsigned short* vtb = kb + (size_t)M_ROWS * H_DIM;

    prep_weights<<<dim3(E_DIM / 64, 3), 256, 0, stream>>>(Wq, Wk, Wv, wt);
    proj_kernel<<<dim3(M_ROWS / 64), 512, 0, stream>>>(x, wt, bq, bk, bv, qb, kb, vtb);
    attn_kernel<<<dim3((T_CTX / 32) * B_SZ), 512, 0, stream>>>(qb, kb, vtb, out);
}